// Round 8
// baseline (145.966 us; speedup 1.0000x reference)
//
#include <hip/hip_runtime.h>
#include <hip/hip_bf16.h>
#include <math.h>

// Problem constants (T=64, B=256, N=512)
#define TT 64
#define BB 256
#define NN 512

typedef __attribute__((ext_vector_type(8)))  short s16x8;   // 8 bf16 = 4 VGPR
typedef __attribute__((ext_vector_type(16))) float f32x16;  // 32x32 C/D frag

// global -> LDS direct DMA, 16B per lane. LDS dest is wave-uniform base
// (HW adds lane*16); global src is per-lane.
__device__ __forceinline__ void gload16(const void* g, void* l) {
  __builtin_amdgcn_global_load_lds(
      (const __attribute__((address_space(1))) unsigned int*)g,
      (__attribute__((address_space(3))) unsigned int*)l, 16, 0, 0);
}

// ---------------------------------------------------------------------------
// Chunk layout (bf16): 1KB chunk = 32 rows x 16 k: element(row,k) at ushort
// index ((k>>3)*32 + (row&31))*8 + (k&7)  == MFMA 32x32x16 A/B fragment order
// (lane l holds row=l&31, k=(l>>5)*8+j). gload16 of a chunk is base + l*16 ->
// lane-contiguous, perfectly coalesced.
// ---------------------------------------------------------------------------

// K0: W -> 3 RNE-bf16 components in chunk layout.
// WT chunk index: ((cg*3 + c)*32 + kc); residual <= 2^-27|W| per weight.
__global__ __launch_bounds__(256) void wprep_kernel(
    const float* __restrict__ W, unsigned short* __restrict__ WT) {
  int i = blockIdx.x * 256 + threadIdx.x;   // i = m*512 + k
  int m = i >> 9, k = i & 511;
  float v = W[i];
  unsigned u0 = __float_as_uint(v);
  unsigned h0 = (u0 + 0x7FFFu + ((u0 >> 16) & 1u)) >> 16;       // RNE bf16
  float f0 = __uint_as_float(h0 << 16);
  float r1 = v - f0;
  unsigned u1 = __float_as_uint(r1);
  unsigned h1 = (u1 + 0x7FFFu + ((u1 >> 16) & 1u)) >> 16;
  float f1 = __uint_as_float(h1 << 16);
  float r2 = r1 - f1;
  unsigned u2 = __float_as_uint(r2);
  unsigned h2 = (u2 + 0x7FFFu + ((u2 >> 16) & 1u)) >> 16;
  int cg = m >> 5, kc = k >> 4;
  size_t base = ((size_t)(cg * 3) * 32 + kc) * 512
              + ((m & 31) + 32 * ((k >> 3) & 1)) * 8 + (k & 7);
  WT[base        ] = (unsigned short)h0;    // comp c at base + c*16384
  WT[base + 16384] = (unsigned short)h1;
  WT[base + 32768] = (unsigned short)h2;
}

// ---------------------------------------------------------------------------
// K1: fused front-end. One block per b. Stage x[:,b,:] (128KB) into LDS once,
// row-means -> spatial LIF (reg/shfl chain), col-means -> temporal gate,
// main gated LIF scan -> bf16 spikes written directly in chunk layout.
// (No per-thread xcol[] array — R7's 64-reg array halved occupancy.)
// ---------------------------------------------------------------------------
__global__ __launch_bounds__(512) void frontend_kernel(
    const float* __restrict__ x, unsigned short* __restrict__ spkT) {
  extern __shared__ float xs[];          // [64][512] = 128 KB
  __shared__ float rms[TT];
  __shared__ float sp[TT];
  int b = blockIdx.x, tid = threadIdx.x;
  int l = tid & 63, w = tid >> 6;        // 8 waves
  #pragma unroll
  for (int p = 0; p < 16; ++p) {
    int f = p * 512 + tid;
    int t = f >> 7, c4 = f & 127;        // row t, float4 col c4
    gload16(x + (size_t)t * (BB * NN) + (size_t)b * NN + c4 * 4,
            (char*)xs + p * 8192 + w * 1024);
  }
  __syncthreads();                       // drains vmcnt(0) before barrier
  #pragma unroll
  for (int j = 0; j < 8; ++j) {          // wave w owns rows w*8..w*8+7
    int t = w * 8 + j;
    float s = 0.f;
    #pragma unroll
    for (int q = 0; q < 8; ++q) s += xs[t * 512 + q * 64 + l];
    #pragma unroll
    for (int off = 32; off; off >>= 1) s += __shfl_xor(s, off);
    if (l == 0) rms[t] = s;
  }
  float cs = 0.f;
  for (int t = 0; t < TT; ++t) cs += xs[t * 512 + tid];
  __syncthreads();
  // spatial LIF scan: wave 0, register chain via shfl broadcast
  if (w == 0) {
    float myrm = rms[l];
    float v = 0.f;
    unsigned long long mask = 0ull;
    #pragma unroll
    for (int t = 0; t < TT; ++t) {
      float m = __shfl(myrm, t) * (1.0f / 512.0f);
      v = v * 0.5f + m;                  // == v - v/2 + m exactly
      if (v >= 1.0f) { mask |= (1ull << t); v = 0.f; }
    }
    sp[l] = (float)((mask >> l) & 1ull);
  }
  __syncthreads();
  float te = (cs * (1.0f / 64.0f) >= 1.0f) ? 1.0f : 0.0f;
  float v = 0.f;
  // chunk-layout bf16 spike store; rg = t*8 + (b>>5) advances 8 chunks per t
  unsigned short* sb = spkT + (size_t)(b >> 5) * 16384 + (tid >> 4) * 512
                     + (b & 31) * 8 + ((tid >> 3) & 1) * 256 + (tid & 7);
  for (int t = 0; t < TT; ++t) {
    float xv = xs[t * 512 + tid];
    float a = xv + (xv * sp[t]) * (xv * te);  // ==xv exactly when a gate is 0
    v = v * 0.5f + a;
    unsigned short s = (v >= 1.0f) ? 0x3F80 : 0;  // bf16 1.0 / 0.0
    sb[(size_t)t * 131072] = s;
    if (s) v = 0.f;
  }
}

// ---------------------------------------------------------------------------
// K2: bf16 MFMA GEMM, 3-component split, 3x16KB buffers, counted vmcnt(4).
// Tile 128x128, grid (128,4), 4 waves (wr 0..1 x wc 0..1), wave = 64x64 out,
// acc[2][2] f32x16 = 64 VGPRs. Per K-step (BK=16): wave stages 4 chunks
// (w==0: A rg 0..3; w>=1: B comp w-1, cg 0..3), reads 2 a-frags + 6 b-frags,
// 12 MFMAs (3 components accumulate into the SAME acc — scale is embedded).
// Pipeline: stage(ks+2) in flight; top-of-iter waits lgkmcnt(0) + vmcnt(4)
// (leaves stage(ks+1)'s 4 loads pending across the barrier).
// ---------------------------------------------------------------------------
__global__ __launch_bounds__(256) void gemm_kernel(
    const unsigned short* __restrict__ AT, const unsigned short* __restrict__ WT,
    float* __restrict__ C, float* __restrict__ pS, float* __restrict__ pQ) {
  __shared__ unsigned char sm[3][16384];
  int tid = threadIdx.x;
  int l = tid & 63, w = tid >> 6;        // 4 waves
  int wr = w >> 1, wc = w & 1;
  int bx = blockIdx.x, by = blockIdx.y;
  int row0 = bx * 128, col0 = by * 128;
  int lr = l & 31, lh = l >> 5;

  f32x16 acc[2][2];
  #pragma unroll
  for (int f = 0; f < 2; ++f)
    #pragma unroll
    for (int g = 0; g < 2; ++g)
      #pragma unroll
      for (int j = 0; j < 16; ++j) acc[f][g][j] = 0.f;

  auto STAGE = [&](unsigned char* lbase, int ks) {
    if (w == 0) {                        // A: 4 chunks (128 rows)
      #pragma unroll
      for (int j = 0; j < 4; ++j)
        gload16((const char*)AT + ((size_t)(bx * 4 + j) * 32 + ks) * 1024 + l * 16,
                lbase + j * 1024);
    } else {                             // B: comp = w-1, 4 col-groups
      int comp = w - 1;
      #pragma unroll
      for (int cg = 0; cg < 4; ++cg)
        gload16((const char*)WT + (((size_t)(by * 4 + cg) * 3 + comp) * 32 + ks) * 1024 + l * 16,
                lbase + 4096 + (cg * 3 + comp) * 1024);
    }
  };

  STAGE(sm[0], 0);
  STAGE(sm[1], 1);
  for (int ks = 0; ks < 32; ++ks) {
    asm volatile("s_waitcnt lgkmcnt(0)" ::: "memory");   // my prev-buf reads done
    if (ks < 31) asm volatile("s_waitcnt vmcnt(4)" ::: "memory");  // stage(ks) landed
    else         asm volatile("s_waitcnt vmcnt(0)" ::: "memory");
    asm volatile("s_barrier" ::: "memory");
    if (ks < 30) STAGE(sm[(ks + 2) % 3], ks + 2);
    const unsigned char* bp = sm[ks % 3];
    s16x8 a[2], bf[2][3];
    #pragma unroll
    for (int f = 0; f < 2; ++f)
      a[f] = *(const s16x8*)(bp + (wr * 2 + f) * 1024 + l * 16);
    #pragma unroll
    for (int g = 0; g < 2; ++g)
      #pragma unroll
      for (int c = 0; c < 3; ++c)
        bf[g][c] = *(const s16x8*)(bp + 4096 + ((wc * 2 + g) * 3 + c) * 1024 + l * 16);
    __builtin_amdgcn_s_setprio(1);
    #pragma unroll
    for (int c = 0; c < 3; ++c)
      #pragma unroll
      for (int f = 0; f < 2; ++f)
        #pragma unroll
        for (int g = 0; g < 2; ++g)
          acc[f][g] = __builtin_amdgcn_mfma_f32_32x32x16_bf16(a[f], bf[g][c], acc[f][g], 0, 0, 0);
    __builtin_amdgcn_s_setprio(0);
  }

  // epilogue: C write + BN partials. C/D frag: col=l&31, row=(j&3)+8*(j>>2)+4*lh.
  // lanes lh=0/1 share a column, different rows -> combine across lane^32.
  #pragma unroll
  for (int g = 0; g < 2; ++g) {
    int col = col0 + wc * 64 + g * 32 + lr;
    float sy = 0.f, sq = 0.f;
    #pragma unroll
    for (int f = 0; f < 2; ++f)
      #pragma unroll
      for (int j = 0; j < 16; ++j) {
        float y = acc[f][g][j];
        int row = row0 + wr * 64 + f * 32 + (j & 3) + 8 * (j >> 2) + 4 * lh;
        C[(size_t)row * NN + col] = y;
        sy += y; sq += y * y;
      }
    sy += __shfl_xor(sy, 32);
    sq += __shfl_xor(sq, 32);
    if (lh == 0) {
      pS[(size_t)col * 256 + bx * 2 + wr] = sy;
      pQ[(size_t)col * 256 + bx * 2 + wr] = sq;
    }
  }
}

// ---------------------------------------------------------------------------
// K3: reduce 256 BN partials per channel -> mu, inv-std
// ---------------------------------------------------------------------------
__global__ __launch_bounds__(512) void bnstatsB_kernel(
    const float* __restrict__ pS, const float* __restrict__ pQ,
    float* __restrict__ mu, float* __restrict__ inv) {
  int tid = threadIdx.x;
  int ch = blockIdx.x * 64 + (tid >> 3), p = tid & 7;
  const float* ps = pS + (size_t)ch * 256 + p * 32;
  const float* pq = pQ + (size_t)ch * 256 + p * 32;
  float s = 0.f, q = 0.f;
  #pragma unroll
  for (int i = 0; i < 32; ++i) { s += ps[i]; q += pq[i]; }
  #pragma unroll
  for (int off = 1; off < 8; off <<= 1) { s += __shfl_xor(s, off); q += __shfl_xor(q, off); }
  if (p == 0) {
    float mean = s * (1.0f / 16384.0f);
    float var  = q * (1.0f / 16384.0f) - mean * mean;
    mu[ch] = mean;
    inv[ch] = 1.0f / sqrtf(var + 1e-5f);
  }
}

// ---------------------------------------------------------------------------
// K4: BN normalize + final LIF scan, in-place on d_out, 16-deep load prefetch
// ---------------------------------------------------------------------------
__global__ __launch_bounds__(256) void final_kernel(
    float* __restrict__ y, const float* __restrict__ mu, const float* __restrict__ inv,
    const float* __restrict__ gamma, const float* __restrict__ beta) {
  int g = blockIdx.x * 256 + threadIdx.x;   // (b, m)
  int b = g >> 9, m = g & 511;
  float MU = mu[m], IV = inv[m], G = gamma[m], BE = beta[m];
  float* p = y + (size_t)b * NN + m;
  const size_t st = (size_t)BB * NN;
  float buf[16], nxt[16];
  #pragma unroll
  for (int j = 0; j < 16; ++j) buf[j] = p[(size_t)j * st];
  float v = 0.f;
  #pragma unroll
  for (int t0 = 0; t0 < 64; t0 += 16) {
    if (t0 + 16 < 64) {
      #pragma unroll
      for (int j = 0; j < 16; ++j) nxt[j] = p[(size_t)(t0 + 16 + j) * st];
    }
    #pragma unroll
    for (int j = 0; j < 16; ++j) {
      float xb = (buf[j] - MU) * IV * G + BE;
      v = v * 0.5f + xb;
      float s = (v >= 1.0f) ? 1.0f : 0.0f;
      p[(size_t)(t0 + j) * st] = s;
      if (s != 0.f) v = 0.f;
    }
    #pragma unroll
    for (int j = 0; j < 16; ++j) buf[j] = nxt[j];
  }
}

// ---------------------------------------------------------------------------
extern "C" void kernel_launch(void* const* d_in, const int* in_sizes, int n_in,
                              void* d_out, int out_size, void* d_ws, size_t ws_size,
                              hipStream_t stream) {
  const float* x     = (const float*)d_in[0];   // [T,B,N]
  const float* W     = (const float*)d_in[1];   // [N,N]
  const float* gamma = (const float*)d_in[2];   // [N]
  const float* beta  = (const float*)d_in[3];   // [N]
  float* out = (float*)d_out;                   // [T,B,N] fp32

  // workspace layout (~19.4 MB)
  char* ws = (char*)d_ws;
  unsigned short* WT   = (unsigned short*)ws;               //  1,572,864
  unsigned short* spkT = (unsigned short*)(ws + 1572864);   // 16,777,216
  float* pS    = (float*)(ws + 18350080);                   //    524,288
  float* pQ    = (float*)(ws + 18874368);                   //    524,288
  float* bn_mu = (float*)(ws + 19398656);                   //      2,048
  float* bn_inv= (float*)(ws + 19400704);                   //      2,048

  wprep_kernel<<<dim3(1024), dim3(256), 0, stream>>>(W, WT);
  frontend_kernel<<<dim3(BB), dim3(512), 131072, stream>>>(x, spkT);
  gemm_kernel<<<dim3(128, 4), dim3(256), 0, stream>>>(spkT, WT, out, pS, pQ);
  bnstatsB_kernel<<<dim3(8), dim3(512), 0, stream>>>(pS, pQ, bn_mu, bn_inv);
  final_kernel<<<dim3(512), dim3(256), 0, stream>>>(out, bn_mu, bn_inv, gamma, beta);
}

// Round 10
// 145.678 us; speedup vs baseline: 1.0020x; 1.0020x over previous
//
#include <hip/hip_runtime.h>
#include <hip/hip_bf16.h>
#include <math.h>

// Problem constants (T=64, B=256, N=512)
#define TT 64
#define BB 256
#define NN 512

typedef __attribute__((ext_vector_type(8)))  short s16x8;   // 8 bf16 = 4 VGPR
typedef __attribute__((ext_vector_type(16))) float f32x16;  // 32x32 C/D frag

// global -> LDS direct DMA, 16B per lane. LDS dest is wave-uniform base
// (HW adds lane*16); global src is per-lane.
__device__ __forceinline__ void gload16(const void* g, void* l) {
  __builtin_amdgcn_global_load_lds(
      (const __attribute__((address_space(1))) unsigned int*)g,
      (__attribute__((address_space(3))) unsigned int*)l, 16, 0, 0);
}

// ---------------------------------------------------------------------------
// Chunk layout (bf16): 1KB chunk = 32 rows x 16 k: element(row,k) at ushort
// index ((k>>3)*32 + (row&31))*8 + (k&7)  == MFMA 32x32x16 A/B fragment order
// (lane l holds row=l&31, k=(l>>5)*8+j). gload16 of a chunk is base + l*16 ->
// lane-contiguous, perfectly coalesced.
// A plane: chunk id = rg*32 + kc (rg = row>>5 in 0..511, kc = k>>4 in 0..31).
// W: 3 comp-major planes of 512KB: chunk id = (comp*16 + cg)*32 + kc.
// ---------------------------------------------------------------------------

// K0: W -> 3 RNE-bf16 components (w0+w1+w2, residual <= 2^-27|W|), chunked.
__global__ __launch_bounds__(256) void wprep_kernel(
    const float* __restrict__ W, unsigned short* __restrict__ WT) {
  int i = blockIdx.x * 256 + threadIdx.x;   // i = m*512 + k
  int m = i >> 9, k = i & 511;
  float v = W[i];
  unsigned u0 = __float_as_uint(v);
  unsigned h0 = (u0 + 0x7FFFu + ((u0 >> 16) & 1u)) >> 16;       // RNE bf16
  float f0 = __uint_as_float(h0 << 16);
  float r1 = v - f0;
  unsigned u1 = __float_as_uint(r1);
  unsigned h1 = (u1 + 0x7FFFu + ((u1 >> 16) & 1u)) >> 16;
  float f1 = __uint_as_float(h1 << 16);
  float r2 = r1 - f1;
  unsigned u2 = __float_as_uint(r2);
  unsigned h2 = (u2 + 0x7FFFu + ((u2 >> 16) & 1u)) >> 16;
  int cg = m >> 5, kc = k >> 4;
  size_t base = ((size_t)cg * 32 + kc) * 512
              + ((m & 31) + 32 * ((k >> 3) & 1)) * 8 + (k & 7);
  WT[base         ] = (unsigned short)h0;   // comp c at base + c*262144
  WT[base + 262144] = (unsigned short)h1;
  WT[base + 524288] = (unsigned short)h2;
}

// ---------------------------------------------------------------------------
// K1: fused front-end (unchanged, absmax 0.0 proven). One block per b.
// ---------------------------------------------------------------------------
__global__ __launch_bounds__(512) void frontend_kernel(
    const float* __restrict__ x, unsigned short* __restrict__ spkT) {
  extern __shared__ float xs[];          // [64][512] = 128 KB
  __shared__ float rms[TT];
  __shared__ float sp[TT];
  int b = blockIdx.x, tid = threadIdx.x;
  int l = tid & 63, w = tid >> 6;        // 8 waves
  #pragma unroll
  for (int p = 0; p < 16; ++p) {
    int f = p * 512 + tid;
    int t = f >> 7, c4 = f & 127;        // row t, float4 col c4
    gload16(x + (size_t)t * (BB * NN) + (size_t)b * NN + c4 * 4,
            (char*)xs + p * 8192 + w * 1024);
  }
  __syncthreads();                       // drains vmcnt(0) before barrier
  #pragma unroll
  for (int j = 0; j < 8; ++j) {          // wave w owns rows w*8..w*8+7
    int t = w * 8 + j;
    float s = 0.f;
    #pragma unroll
    for (int q = 0; q < 8; ++q) s += xs[t * 512 + q * 64 + l];
    #pragma unroll
    for (int off = 32; off; off >>= 1) s += __shfl_xor(s, off);
    if (l == 0) rms[t] = s;
  }
  float cs = 0.f;
  for (int t = 0; t < TT; ++t) cs += xs[t * 512 + tid];
  __syncthreads();
  // spatial LIF scan: wave 0, register chain via shfl broadcast
  if (w == 0) {
    float myrm = rms[l];
    float v = 0.f;
    unsigned long long mask = 0ull;
    #pragma unroll
    for (int t = 0; t < TT; ++t) {
      float m = __shfl(myrm, t) * (1.0f / 512.0f);
      v = v * 0.5f + m;                  // == v - v/2 + m exactly
      if (v >= 1.0f) { mask |= (1ull << t); v = 0.f; }
    }
    sp[l] = (float)((mask >> l) & 1ull);
  }
  __syncthreads();
  float te = (cs * (1.0f / 64.0f) >= 1.0f) ? 1.0f : 0.0f;
  float v = 0.f;
  // chunk-layout bf16 spike store; rg = t*8 + (b>>5) advances 8 chunks per t
  unsigned short* sb = spkT + (size_t)(b >> 5) * 16384 + (tid >> 4) * 512
                     + (b & 31) * 8 + ((tid >> 3) & 1) * 256 + (tid & 7);
  for (int t = 0; t < TT; ++t) {
    float xv = xs[t * 512 + tid];
    float a = xv + (xv * sp[t]) * (xv * te);  // ==xv exactly when a gate is 0
    v = v * 0.5f + a;
    unsigned short s = (v >= 1.0f) ? 0x3F80 : 0;  // bf16 1.0 / 0.0
    sb[(size_t)t * 131072] = s;
    if (s) v = 0.f;
  }
}

// ---------------------------------------------------------------------------
// K2: bf16 MFMA GEMM, BK=32, 2x32KB double-buffer (64KB -> 2 blocks/CU).
// Tile 128x128, grid (128,4), 4 waves (2x2), wave = 64x64 out, acc[2][2].
// Per K-tile (32 k): STAGE = 32 chunks (A 8 + B 24), 8 gload16 PER WAVE
// (balanced). Loop iter: lgkmcnt(0); vmcnt(0); s_barrier; STAGE(kt+1);
// per kc2: {2 a-reads + 6 b-reads; 12 MFMA}. 24 MFMA+16 ds_read per iter
// (~2x the staging latency) -> latency hidden; 16 barriers total (was 32).
// ---------------------------------------------------------------------------
__global__ __launch_bounds__(256) void gemm_kernel(
    const unsigned short* __restrict__ AT, const unsigned short* __restrict__ WT,
    float* __restrict__ C, float* __restrict__ pS, float* __restrict__ pQ) {
  __shared__ unsigned char sm[2][32768];
  int tid = threadIdx.x;
  int l = tid & 63, w = tid >> 6;        // 4 waves
  int wr = w >> 1, wc = w & 1;
  int bx = blockIdx.x, by = blockIdx.y;
  int row0 = bx * 128, col0 = by * 128;
  int lr = l & 31, lh = l >> 5;

  f32x16 acc[2][2];
  #pragma unroll
  for (int f = 0; f < 2; ++f)
    #pragma unroll
    for (int g = 0; g < 2; ++g)
      #pragma unroll
      for (int j = 0; j < 16; ++j) acc[f][g][j] = 0.f;

  // A chunks c=0..7: rg_loc = c>>1, kc2 = c&1, LDS at c*1024.
  // B chunks c=0..23 (comp-major): comp = c>>3, cg = (c>>1)&3, kc2 = c&1,
  // LDS at 8192 + c*1024. Wave w takes A {w, w+4}, B {w, w+4, ..., w+20}.
  auto STAGE = [&](unsigned char* lbase, int kt) {
    #pragma unroll
    for (int j = 0; j < 2; ++j) {
      int c = j * 4 + w;
      int rg = bx * 4 + (c >> 1), kc = kt * 2 + (c & 1);
      gload16((const char*)AT + ((size_t)rg * 32 + kc) * 1024 + l * 16,
              lbase + c * 1024);
    }
    #pragma unroll
    for (int j = 0; j < 6; ++j) {
      int c = j * 4 + w;
      int comp = c >> 3, cg = (c >> 1) & 3, kc = kt * 2 + (c & 1);
      gload16((const char*)WT + (((size_t)comp * 16 + by * 4 + cg) * 32 + kc) * 1024 + l * 16,
              lbase + 8192 + c * 1024);
    }
  };

  STAGE(sm[0], 0);
  #pragma unroll
  for (int kt = 0; kt < 16; ++kt) {
    asm volatile("s_waitcnt lgkmcnt(0)" ::: "memory");  // my prev-buf reads done
    asm volatile("s_waitcnt vmcnt(0)" ::: "memory");    // my stage of buf landed
    asm volatile("s_barrier" ::: "memory");             // all waves agree
    if (kt < 15) STAGE(sm[(kt + 1) & 1], kt + 1);       // refill freed buffer
    const unsigned char* bp = sm[kt & 1];
    #pragma unroll
    for (int kc2 = 0; kc2 < 2; ++kc2) {
      s16x8 a[2], bf[2][3];
      #pragma unroll
      for (int f = 0; f < 2; ++f)
        a[f] = *(const s16x8*)(bp + ((wr * 2 + f) * 2 + kc2) * 1024 + l * 16);
      #pragma unroll
      for (int g = 0; g < 2; ++g)
        #pragma unroll
        for (int c = 0; c < 3; ++c)
          bf[g][c] = *(const s16x8*)(bp + 8192 + ((c * 4 + wc * 2 + g) * 2 + kc2) * 1024 + l * 16);
      __builtin_amdgcn_s_setprio(1);
      #pragma unroll
      for (int c = 0; c < 3; ++c)
        #pragma unroll
        for (int f = 0; f < 2; ++f)
          #pragma unroll
          for (int g = 0; g < 2; ++g)
            acc[f][g] = __builtin_amdgcn_mfma_f32_32x32x16_bf16(a[f], bf[g][c], acc[f][g], 0, 0, 0);
      __builtin_amdgcn_s_setprio(0);
    }
  }

  // epilogue: C write + BN partials. C/D frag: col=l&31, row=(j&3)+8*(j>>2)+4*lh.
  // lanes lh=0/1 share a column, different rows -> combine across lane^32.
  #pragma unroll
  for (int g = 0; g < 2; ++g) {
    int col = col0 + wc * 64 + g * 32 + lr;
    float sy = 0.f, sq = 0.f;
    #pragma unroll
    for (int f = 0; f < 2; ++f)
      #pragma unroll
      for (int j = 0; j < 16; ++j) {
        float y = acc[f][g][j];
        int row = row0 + wr * 64 + f * 32 + (j & 3) + 8 * (j >> 2) + 4 * lh;
        C[(size_t)row * NN + col] = y;
        sy += y; sq += y * y;
      }
    sy += __shfl_xor(sy, 32);
    sq += __shfl_xor(sq, 32);
    if (lh == 0) {
      pS[(size_t)col * 256 + bx * 2 + wr] = sy;
      pQ[(size_t)col * 256 + bx * 2 + wr] = sq;
    }
  }
}

// ---------------------------------------------------------------------------
// K3: reduce 256 BN partials per channel -> mu, inv-std
// ---------------------------------------------------------------------------
__global__ __launch_bounds__(512) void bnstatsB_kernel(
    const float* __restrict__ pS, const float* __restrict__ pQ,
    float* __restrict__ mu, float* __restrict__ inv) {
  int tid = threadIdx.x;
  int ch = blockIdx.x * 64 + (tid >> 3), p = tid & 7;
  const float* ps = pS + (size_t)ch * 256 + p * 32;
  const float* pq = pQ + (size_t)ch * 256 + p * 32;
  float s = 0.f, q = 0.f;
  #pragma unroll
  for (int i = 0; i < 32; ++i) { s += ps[i]; q += pq[i]; }
  #pragma unroll
  for (int off = 1; off < 8; off <<= 1) { s += __shfl_xor(s, off); q += __shfl_xor(q, off); }
  if (p == 0) {
    float mean = s * (1.0f / 16384.0f);
    float var  = q * (1.0f / 16384.0f) - mean * mean;
    mu[ch] = mean;
    inv[ch] = 1.0f / sqrtf(var + 1e-5f);
  }
}

// ---------------------------------------------------------------------------
// K4: BN normalize + final LIF scan, in-place on d_out, 16-deep load prefetch
// ---------------------------------------------------------------------------
__global__ __launch_bounds__(256) void final_kernel(
    float* __restrict__ y, const float* __restrict__ mu, const float* __restrict__ inv,
    const float* __restrict__ gamma, const float* __restrict__ beta) {
  int g = blockIdx.x * 256 + threadIdx.x;   // (b, m)
  int b = g >> 9, m = g & 511;
  float MU = mu[m], IV = inv[m], G = gamma[m], BE = beta[m];
  float* p = y + (size_t)b * NN + m;
  const size_t st = (size_t)BB * NN;
  float buf[16], nxt[16];
  #pragma unroll
  for (int j = 0; j < 16; ++j) buf[j] = p[(size_t)j * st];
  float v = 0.f;
  #pragma unroll
  for (int t0 = 0; t0 < 64; t0 += 16) {
    if (t0 + 16 < 64) {
      #pragma unroll
      for (int j = 0; j < 16; ++j) nxt[j] = p[(size_t)(t0 + 16 + j) * st];
    }
    #pragma unroll
    for (int j = 0; j < 16; ++j) {
      float xb = (buf[j] - MU) * IV * G + BE;
      v = v * 0.5f + xb;
      float s = (v >= 1.0f) ? 1.0f : 0.0f;
      p[(size_t)(t0 + j) * st] = s;
      if (s != 0.f) v = 0.f;
    }
    #pragma unroll
    for (int j = 0; j < 16; ++j) buf[j] = nxt[j];
  }
}

// ---------------------------------------------------------------------------
extern "C" void kernel_launch(void* const* d_in, const int* in_sizes, int n_in,
                              void* d_out, int out_size, void* d_ws, size_t ws_size,
                              hipStream_t stream) {
  const float* x     = (const float*)d_in[0];   // [T,B,N]
  const float* W     = (const float*)d_in[1];   // [N,N]
  const float* gamma = (const float*)d_in[2];   // [N]
  const float* beta  = (const float*)d_in[3];   // [N]
  float* out = (float*)d_out;                   // [T,B,N] fp32

  // workspace layout (~19.4 MB)
  char* ws = (char*)d_ws;
  unsigned short* WT   = (unsigned short*)ws;               //  1,572,864
  unsigned short* spkT = (unsigned short*)(ws + 1572864);   // 16,777,216
  float* pS    = (float*)(ws + 18350080);                   //    524,288
  float* pQ    = (float*)(ws + 18874368);                   //    524,288
  float* bn_mu = (float*)(ws + 19398656);                   //      2,048
  float* bn_inv= (float*)(ws + 19400704);                   //      2,048

  wprep_kernel<<<dim3(1024), dim3(256), 0, stream>>>(W, WT);
  frontend_kernel<<<dim3(BB), dim3(512), 131072, stream>>>(x, spkT);
  gemm_kernel<<<dim3(128, 4), dim3(256), 0, stream>>>(spkT, WT, out, pS, pQ);
  bnstatsB_kernel<<<dim3(8), dim3(512), 0, stream>>>(pS, pQ, bn_mu, bn_inv);
  final_kernel<<<dim3(512), dim3(256), 0, stream>>>(out, bn_mu, bn_inv, gamma, beta);
}